// Round 5
// baseline (264.519 us; speedup 1.0000x reference)
//
#include <hip/hip_runtime.h>
#include <hip/hip_bf16.h>

// SelfAttention1d  B=16, C=512, L=1024
// R5: revert R4 pipeline (was neutral-to-negative, per m131-m140 this structure
//     plateaus regardless). R3 core restored (46us qkv, 0 conflicts).
//     NEW: softmax eliminated as a materialized pass — row_stats kernel
//     computes {max, 1/sum} per score row; attn_pv applies exp in-register on
//     the B-fragments between ds_read and MFMA. Packed T-store epilogues
//     everywhere except the v-part of fused QKV.

#define BB 16
#define CC 512
#define LL 1024

typedef __bf16 bf16x8 __attribute__((ext_vector_type(8)));
typedef float  f32x4  __attribute__((ext_vector_type(4)));

__device__ inline unsigned short bf16_bits(float f) {
  __hip_bfloat16 h = __float2bfloat16(f);
  return __builtin_bit_cast(unsigned short, h);
}
__device__ inline float bits_lo(unsigned int u) {
  return __builtin_bit_cast(float, u << 16);
}
__device__ inline float bits_hi(unsigned int u) {
  return __builtin_bit_cast(float, u & 0xffff0000u);
}

// ---------------- BN stats: one block per channel ----------------
__global__ __launch_bounds__(256) void bn_stats(
    const float* __restrict__ x, const float* __restrict__ gamma,
    const float* __restrict__ beta, float* __restrict__ scl,
    float* __restrict__ sft) {
  int c = blockIdx.x;
  int t = threadIdx.x;
  float s = 0.f, s2 = 0.f;
  for (int b = 0; b < BB; ++b) {
    float4 v = ((const float4*)(x + ((size_t)(b * CC + c)) * LL))[t];
    s  += v.x + v.y + v.z + v.w;
    s2 += v.x * v.x + v.y * v.y + v.z * v.z + v.w * v.w;
  }
  for (int m = 32; m; m >>= 1) { s += __shfl_xor(s, m, 64); s2 += __shfl_xor(s2, m, 64); }
  __shared__ float rs[4], rs2[4];
  int wave = t >> 6, lane = t & 63;
  if (lane == 0) { rs[wave] = s; rs2[wave] = s2; }
  __syncthreads();
  if (t == 0) {
    float S  = rs[0] + rs[1] + rs[2] + rs[3];
    float S2 = rs2[0] + rs2[1] + rs2[2] + rs2[3];
    float mean = S * (1.f / 16384.f);
    float var  = S2 * (1.f / 16384.f) - mean * mean;
    float sc = gamma[c] * rsqrtf(var + 1e-5f);
    scl[c] = sc;
    sft[c] = beta[c] - mean * sc;
  }
}

// ---------------- weight casts: Wq|Wk|Wv concat, Wp separate ----------------
__global__ __launch_bounds__(256) void cast4(
    const float* __restrict__ Wq, const float* __restrict__ Wk,
    const float* __restrict__ Wv, const float* __restrict__ Wp,
    __hip_bfloat16* __restrict__ Wqkv, __hip_bfloat16* __restrict__ Wpb) {
  int m = blockIdx.y;
  const float* src = m == 0 ? Wq : m == 1 ? Wk : m == 2 ? Wv : Wp;
  __hip_bfloat16* dst = m < 3 ? Wqkv + (size_t)m * 262144 : Wpb;
  int i = blockIdx.x * 256 + threadIdx.x;
  float4 v = ((const float4*)src)[i];
  ushort4 o;
  o.x = bf16_bits(v.x); o.y = bf16_bits(v.y);
  o.z = bf16_bits(v.z); o.w = bf16_bits(v.w);
  ((ushort4*)dst)[i] = o;
}

// ---------------- normalize + transpose: x [B][C][L] -> hnT [B][L][C] bf16 ----
__global__ __launch_bounds__(256) void norm_t(
    const float* __restrict__ x, const float* __restrict__ scl,
    const float* __restrict__ sft, __hip_bfloat16* __restrict__ hnT) {
  __shared__ float tile[32][33];
  int l0 = blockIdx.x * 32, c0 = blockIdx.y * 32, b = blockIdx.z;
  int t = threadIdx.x;
#pragma unroll
  for (int i = 0; i < 4; ++i) {
    int idx = t + i * 256;
    int cc = idx >> 5, ll = idx & 31;
    tile[cc][ll] = x[((size_t)(b * CC + c0 + cc)) * LL + l0 + ll];
  }
  __syncthreads();
#pragma unroll
  for (int i = 0; i < 2; ++i) {
    int idx = t + i * 256;
    int ll = idx >> 4, cc = (idx & 15) * 2;
    float v0 = tile[cc][ll] * scl[c0 + cc] + sft[c0 + cc];
    float v1 = tile[cc + 1][ll] * scl[c0 + cc + 1] + sft[c0 + cc + 1];
    ushort2 o; o.x = bf16_bits(v0); o.y = bf16_bits(v1);
    *(ushort2*)(hnT + ((size_t)(b * LL + l0 + ll)) * CC + c0 + cc) = o;
  }
}

// ---------------- row stats: per score row -> {max, 1/sum(exp)} ----------------
__global__ __launch_bounds__(256) void row_stats(
    const __hip_bfloat16* __restrict__ S, float2* __restrict__ st) {
  int wave = threadIdx.x >> 6, lane = threadIdx.x & 63;
  size_t row = (size_t)blockIdx.x * 4 + wave;
  const uint4* p = (const uint4*)(S + row * 1024);
  uint4 r0 = p[lane * 2], r1 = p[lane * 2 + 1];
  float f[16];
  unsigned int w[8] = {r0.x, r0.y, r0.z, r0.w, r1.x, r1.y, r1.z, r1.w};
#pragma unroll
  for (int i = 0; i < 8; ++i) { f[2 * i] = bits_lo(w[i]); f[2 * i + 1] = bits_hi(w[i]); }
  float mx = f[0];
#pragma unroll
  for (int i = 1; i < 16; ++i) mx = fmaxf(mx, f[i]);
  for (int m = 32; m; m >>= 1) mx = fmaxf(mx, __shfl_xor(mx, m, 64));
  float s = 0.f;
#pragma unroll
  for (int i = 0; i < 16; ++i) s += __expf(f[i] - mx);
  for (int m = 32; m; m >>= 1) s += __shfl_xor(s, m, 64);
  if (lane == 0) st[row] = make_float2(mx, 1.f / s);
}

// ---------------- GEMM core (R3): acc += A[128xK] * B[128xK]^T ----------------
// LDS 128x32 per operand; k-chunks XOR-swizzled (col = q ^ ((row>>1)&3)) so
// fragment reads are 2-way-only bank aliased (free, m136).
__device__ inline void glds(const __hip_bfloat16* g, __hip_bfloat16* l) {
  __builtin_amdgcn_global_load_lds(
      (__attribute__((address_space(1))) void*)(void*)g,
      (__attribute__((address_space(3))) void*)l, 16, 0, 0);
}

__device__ __forceinline__ void gemm_core(
    const __hip_bfloat16* __restrict__ A, int lda,
    const __hip_bfloat16* __restrict__ B, int ldb, int K,
    __hip_bfloat16* sA, __hip_bfloat16* sB, f32x4 (&acc)[4][4]) {
  const int tid = threadIdx.x;
  const int wave = tid >> 6, lane = tid & 63;
  const int wm = (wave >> 1) * 64, wn = (wave & 1) * 64;
  const int row0 = tid >> 2;
  const int ke0 = (((tid & 3) ^ ((tid >> 3) & 3)) * 8);
  const int fr = lane & 15;
  const int q = lane >> 4;
  const int colA = ((q ^ ((fr >> 1) & 3)) * 8);
  for (int k0 = 0; k0 < K; k0 += 32) {
    __syncthreads();
#pragma unroll
    for (int it = 0; it < 2; ++it) {
      const __hip_bfloat16* ga = A + (size_t)(it * 64 + row0) * lda + (k0 + ke0);
      const __hip_bfloat16* gb = B + (size_t)(it * 64 + row0) * ldb + (k0 + ke0);
      glds(ga, sA + (it * 256 + wave * 64) * 8);
      glds(gb, sB + (it * 256 + wave * 64) * 8);
    }
    __syncthreads();
    bf16x8 af[4], bfr[4];
#pragma unroll
    for (int i = 0; i < 4; ++i) {
      af[i]  = *(const bf16x8*)(sA + (wm + i * 16 + fr) * 32 + colA);
      bfr[i] = *(const bf16x8*)(sB + (wn + i * 16 + fr) * 32 + colA);
    }
#pragma unroll
    for (int i = 0; i < 4; ++i)
#pragma unroll
      for (int j = 0; j < 4; ++j)
        acc[i][j] = __builtin_amdgcn_mfma_f32_16x16x32_bf16(af[i], bfr[j], acc[i][j], 0, 0, 0);
  }
}

// ---------------- fused QKV: [1536x512] x hnT -> qT,kT (packed T), v (natural) -
__global__ __launch_bounds__(256, 3) void gemm_qkv(
    const __hip_bfloat16* __restrict__ Wb, const __hip_bfloat16* __restrict__ hnT,
    __hip_bfloat16* __restrict__ qT, __hip_bfloat16* __restrict__ kT,
    __hip_bfloat16* __restrict__ vN,
    const float* __restrict__ bq, const float* __restrict__ bk,
    const float* __restrict__ bv) {
  __shared__ __align__(16) __hip_bfloat16 sA[128 * 32];
  __shared__ __align__(16) __hip_bfloat16 sB[128 * 32];
  const int bat = blockIdx.z;
  const int m0 = blockIdx.y * 128, n0 = blockIdx.x * 128;
  f32x4 acc[4][4] = {};
  gemm_core(Wb + (size_t)m0 * 512, 512,
            hnT + (size_t)bat * LL * CC + (size_t)n0 * 512, 512, 512, sA, sB, acc);
  const int lane = threadIdx.x & 63, wave = threadIdx.x >> 6;
  const int wm = (wave >> 1) * 64, wn = (wave & 1) * 64;
  const int crow = (lane >> 4) * 4, ccol = lane & 15;
  const int id = m0 >> 9;
  const int mloc0 = m0 & 511;
  const float* bias = id == 0 ? bq : id == 1 ? bk : bv;
  if (id < 2) {
    __hip_bfloat16* D = (id == 0 ? qT : kT) + (size_t)bat * LL * CC;
#pragma unroll
    for (int i = 0; i < 4; ++i) {
      int mg = mloc0 + wm + i * 16 + crow;
      float bv4[4];
#pragma unroll
      for (int r = 0; r < 4; ++r) bv4[r] = bias[mg + r];
#pragma unroll
      for (int j = 0; j < 4; ++j) {
        int ng = n0 + wn + j * 16 + ccol;
        ushort4 o;
        o.x = bf16_bits(acc[i][j][0] + bv4[0]);
        o.y = bf16_bits(acc[i][j][1] + bv4[1]);
        o.z = bf16_bits(acc[i][j][2] + bv4[2]);
        o.w = bf16_bits(acc[i][j][3] + bv4[3]);
        *(ushort4*)(D + (size_t)ng * 512 + mg) = o;
      }
    }
  } else {
    __hip_bfloat16* D = vN + (size_t)bat * CC * LL;
#pragma unroll
    for (int i = 0; i < 4; ++i) {
      int mg = mloc0 + wm + i * 16 + crow;
      float bv4[4];
#pragma unroll
      for (int r = 0; r < 4; ++r) bv4[r] = bias[mg + r];
#pragma unroll
      for (int j = 0; j < 4; ++j) {
        int ng = n0 + wn + j * 16 + ccol;
#pragma unroll
        for (int r = 0; r < 4; ++r)
          D[(size_t)(mg + r) * 1024 + ng] = __float2bfloat16(acc[i][j][r] + bv4[r]);
      }
    }
  }
}

// ---------------- S GEMM: A=kT (m=j), B=qT (n=i), packed T-store D[i][j] ------
__global__ __launch_bounds__(256, 3) void gemm_s(
    const __hip_bfloat16* __restrict__ kT, const __hip_bfloat16* __restrict__ qT,
    __hip_bfloat16* __restrict__ Sb) {
  __shared__ __align__(16) __hip_bfloat16 sA[128 * 32];
  __shared__ __align__(16) __hip_bfloat16 sB[128 * 32];
  const int bat = blockIdx.z;
  const int m0 = blockIdx.y * 128, n0 = blockIdx.x * 128;
  f32x4 acc[4][4] = {};
  const size_t sLC = (size_t)LL * CC;
  gemm_core(kT + (size_t)bat * sLC + (size_t)m0 * 512, 512,
            qT + (size_t)bat * sLC + (size_t)n0 * 512, 512, 512, sA, sB, acc);
  const int lane = threadIdx.x & 63, wave = threadIdx.x >> 6;
  const int wm = (wave >> 1) * 64, wn = (wave & 1) * 64;
  const int crow = (lane >> 4) * 4, ccol = lane & 15;
  const float scale = 0.04419417382415922f;
  __hip_bfloat16* Db = Sb + (size_t)bat * LL * LL;
#pragma unroll
  for (int j = 0; j < 4; ++j) {
    int ng = n0 + wn + j * 16 + ccol;
#pragma unroll
    for (int i = 0; i < 4; ++i) {
      int mg = m0 + wm + i * 16 + crow;
      ushort4 o;
      o.x = bf16_bits(acc[i][j][0] * scale);
      o.y = bf16_bits(acc[i][j][1] * scale);
      o.z = bf16_bits(acc[i][j][2] * scale);
      o.w = bf16_bits(acc[i][j][3] * scale);
      *(ushort4*)(Db + (size_t)ng * 1024 + mg) = o;
    }
  }
}

// ---------------- PV with fused softmax: A=vN, B=exp(Sb-m)*linv ---------------
// D[n=i][m=c] packed T-store = HT [i][c].
__global__ __launch_bounds__(256, 3) void attn_pv(
    const __hip_bfloat16* __restrict__ vN, const __hip_bfloat16* __restrict__ Sb,
    const float2* __restrict__ st, __hip_bfloat16* __restrict__ HT) {
  __shared__ __align__(16) __hip_bfloat16 sA[128 * 32];
  __shared__ __align__(16) __hip_bfloat16 sB[128 * 32];
  __shared__ float sM[128], sLi[128];
  const int bat = blockIdx.z;
  const int m0 = blockIdx.y * 128;   // c
  const int n0 = blockIdx.x * 128;   // i
  const int tid = threadIdx.x;
  if (tid < 128) {
    float2 s = st[(size_t)bat * LL + n0 + tid];
    sM[tid] = s.x; sLi[tid] = s.y;
  }
  const __hip_bfloat16* A = vN + (size_t)bat * CC * LL + (size_t)m0 * 1024;
  const __hip_bfloat16* B = Sb + (size_t)bat * LL * LL + (size_t)n0 * 1024;
  const int wave = tid >> 6, lane = tid & 63;
  const int wm = (wave >> 1) * 64, wn = (wave & 1) * 64;
  const int row0 = tid >> 2;
  const int ke0 = (((tid & 3) ^ ((tid >> 3) & 3)) * 8);
  const int fr = lane & 15;
  const int q = lane >> 4;
  const int colA = ((q ^ ((fr >> 1) & 3)) * 8);
  f32x4 acc[4][4] = {};
  for (int k0 = 0; k0 < 1024; k0 += 32) {
    __syncthreads();
#pragma unroll
    for (int it = 0; it < 2; ++it) {
      glds(A + (size_t)(it * 64 + row0) * 1024 + (k0 + ke0),
           sA + (it * 256 + wave * 64) * 8);
      glds(B + (size_t)(it * 64 + row0) * 1024 + (k0 + ke0),
           sB + (it * 256 + wave * 64) * 8);
    }
    __syncthreads();
    bf16x8 af[4], bfr[4];
#pragma unroll
    for (int i = 0; i < 4; ++i)
      af[i] = *(const bf16x8*)(sA + (wm + i * 16 + fr) * 32 + colA);
#pragma unroll
    for (int j = 0; j < 4; ++j) {
      int rrow = wn + j * 16 + fr;
      float mrow = sM[rrow], li = sLi[rrow];
      bf16x8 raw = *(const bf16x8*)(sB + rrow * 32 + colA);
      bf16x8 p;
#pragma unroll
      for (int e = 0; e < 8; ++e)
        p[e] = (__bf16)(__expf((float)raw[e] - mrow) * li);
      bfr[j] = p;
    }
#pragma unroll
    for (int i = 0; i < 4; ++i)
#pragma unroll
      for (int j = 0; j < 4; ++j)
        acc[i][j] = __builtin_amdgcn_mfma_f32_16x16x32_bf16(af[i], bfr[j], acc[i][j], 0, 0, 0);
  }
  const int crow = (lane >> 4) * 4, ccol = lane & 15;
  __hip_bfloat16* Db = HT + (size_t)bat * LL * CC;
#pragma unroll
  for (int j = 0; j < 4; ++j) {
    int ng = n0 + wn + j * 16 + ccol;
#pragma unroll
    for (int i = 0; i < 4; ++i) {
      int mg = m0 + wm + i * 16 + crow;
      ushort4 o;
      o.x = bf16_bits(acc[i][j][0]);
      o.y = bf16_bits(acc[i][j][1]);
      o.z = bf16_bits(acc[i][j][2]);
      o.w = bf16_bits(acc[i][j][3]);
      *(ushort4*)(Db + (size_t)ng * 512 + mg) = o;
    }
  }
}

// ---------------- proj GEMM, fp32 T-store: D[n][m] = acc + bias[n] + resid ----
__global__ __launch_bounds__(256, 3) void gemm_f32t(
    const __hip_bfloat16* __restrict__ A, int lda, size_t strideA,
    const __hip_bfloat16* __restrict__ B, int ldb,
    float* __restrict__ D, int ldd, size_t strideD,
    const float* __restrict__ bias, const float* __restrict__ resid, int K) {
  __shared__ __align__(16) __hip_bfloat16 sA[128 * 32];
  __shared__ __align__(16) __hip_bfloat16 sB[128 * 32];
  const int bat = blockIdx.z;
  const int m0 = blockIdx.y * 128, n0 = blockIdx.x * 128;
  f32x4 acc[4][4] = {};
  gemm_core(A + (size_t)bat * strideA + (size_t)m0 * lda, lda,
            B + (size_t)n0 * ldb, ldb, K, sA, sB, acc);
  const int lane = threadIdx.x & 63, wave = threadIdx.x >> 6;
  const int wm = (wave >> 1) * 64, wn = (wave & 1) * 64;
  const int crow = (lane >> 4) * 4, ccol = lane & 15;
  float* Db = D + (size_t)bat * strideD;
  const float* Rb = resid + (size_t)bat * strideD;
#pragma unroll
  for (int j = 0; j < 4; ++j) {
    int ng = n0 + wn + j * 16 + ccol;
    float bn = bias[ng];
#pragma unroll
    for (int i = 0; i < 4; ++i) {
      int mg = m0 + wm + i * 16 + crow;
      float4 r = *(const float4*)(Rb + (size_t)ng * ldd + mg);
      float4 o;
      o.x = acc[i][j][0] + bn + r.x;
      o.y = acc[i][j][1] + bn + r.y;
      o.z = acc[i][j][2] + bn + r.z;
      o.w = acc[i][j][3] + bn + r.w;
      *(float4*)(Db + (size_t)ng * ldd + mg) = o;
    }
  }
}

extern "C" void kernel_launch(void* const* d_in, const int* in_sizes, int n_in,
                              void* d_out, int out_size, void* d_ws, size_t ws_size,
                              hipStream_t stream) {
  const float* x     = (const float*)d_in[0];
  const float* gamma = (const float*)d_in[1];
  const float* beta  = (const float*)d_in[2];
  const float* Wq    = (const float*)d_in[3];
  const float* bq    = (const float*)d_in[4];
  const float* Wk    = (const float*)d_in[5];
  const float* bk    = (const float*)d_in[6];
  const float* Wv    = (const float*)d_in[7];
  const float* bv    = (const float*)d_in[8];
  const float* Wp    = (const float*)d_in[9];
  const float* bp    = (const float*)d_in[10];
  float* out = (float*)d_out;

  char* ws = (char*)d_ws;
  float* scl = (float*)ws;
  float* sft = scl + 512;
  __hip_bfloat16* Wqkvb = (__hip_bfloat16*)(ws + 4096);   // 1536x512
  __hip_bfloat16* Wpb  = Wqkvb + 786432;                  // 512x512
  __hip_bfloat16* hnT  = Wpb + 262144;                    // [B][L][C]
  __hip_bfloat16* qT   = hnT + 8388608;                   // [B][L][C]
  __hip_bfloat16* kT   = qT + 8388608;                    // [B][L][C]
  __hip_bfloat16* vN   = kT + 8388608;                    // [B][C][L]
  __hip_bfloat16* Sb   = vN + 8388608;                    // [B][L][L] bf16
  float2* stats = (float2*)(Sb + 16777216);               // [B][L]
  __hip_bfloat16* HT   = hnT;                             // reuse after QKV

  const size_t sLC = (size_t)LL * CC;
  const size_t sCL = (size_t)CC * LL;

  bn_stats<<<512, 256, 0, stream>>>(x, gamma, beta, scl, sft);
  cast4<<<dim3(256, 4), 256, 0, stream>>>(Wq, Wk, Wv, Wp, Wqkvb, Wpb);
  norm_t<<<dim3(32, 16, 16), 256, 0, stream>>>(x, scl, sft, hnT);

  // qT,kT packed [L][C]; v natural [C][L]
  gemm_qkv<<<dim3(8, 12, 16), 256, 0, stream>>>(Wqkvb, hnT, qT, kT, vN, bq, bk, bv);
  // Sb[i][j] = qT·kT^T * C^-0.5 (raw scores, bf16)
  gemm_s<<<dim3(8, 8, 16), 256, 0, stream>>>(kT, qT, Sb);
  // per-row {max, 1/sum(exp)}
  row_stats<<<4096, 256, 0, stream>>>(Sb, stats);
  // HT[i][c] = softmax(S)·V^T with exp fused on B-fragments
  attn_pv<<<dim3(8, 4, 16), 256, 0, stream>>>(vN, Sb, stats, HT);
  // out[c][i] = Wp·H + bp + x
  gemm_f32t<<<dim3(4, 8, 16), 256, 0, stream>>>(
      HT, 512, sLC, Wpb, 512, out, 1024, sCL, bp, x, 512);
}